// Round 4
// baseline (107.426 us; speedup 1.0000x reference)
//
#include <hip/hip_runtime.h>
#include <hip/hip_bf16.h>

// Problem: out[b] = (inv(A[a[b]]) @ B_rep[a[b]] @ A[a[b]]) @ x[b]
// BATCH=500000, DIM=16, N_ACTIONS=8
// Inputs (setup_inputs order): x[500000*16] f32, a[500000] i32, A[8*16*16] f32, B_rep[8*16*16] f32
// Output: [500000*16] f32

#define N_ACTIONS 8
#define DIM 16
// Action stride in floats for the LDS copy of W. 260 % 32 == 4, so the 8
// actions' ds_read_b128 at a uniform (i,j) offset land in 8 disjoint 4-bank
// groups -> conflict-free. 260*4 = 1040 B is 16-B aligned -> b128 loads legal.
#define W_STRIDE 260

// ---------------------------------------------------------------------------
// Kernel 1: per action n, compute W[n] = inv(A[n]) @ B_rep[n] @ A[n]
// One block of 256 threads per action; thread (i,j) owns element (i,j).
// Gauss-Jordan with partial pivoting in LDS (A is near-identity, well-cond).
// ---------------------------------------------------------------------------
__global__ __launch_bounds__(256) void compute_W_kernel(
    const float* __restrict__ A, const float* __restrict__ Brep,
    float* __restrict__ Wg) {
  __shared__ float M[DIM][DIM + 1];
  __shared__ float Inv[DIM][DIM + 1];
  __shared__ float As[DIM][DIM + 1];
  __shared__ float Bs[DIM][DIM + 1];
  __shared__ float Cs[DIM][DIM + 1];
  __shared__ int s_piv;

  const int n = blockIdx.x;
  const int tid = threadIdx.x;
  const int i = tid >> 4;
  const int j = tid & 15;

  const float a_ij = A[n * 256 + i * 16 + j];
  M[i][j] = a_ij;
  As[i][j] = a_ij;
  Bs[i][j] = Brep[n * 256 + i * 16 + j];
  Inv[i][j] = (i == j) ? 1.0f : 0.0f;
  __syncthreads();

  for (int k = 0; k < DIM; ++k) {
    // --- partial pivot search (single thread; 16 elements, trivial) ---
    if (tid == 0) {
      int p = k;
      float best = fabsf(M[k][k]);
      for (int r = k + 1; r < DIM; ++r) {
        float v = fabsf(M[r][k]);
        if (v > best) { best = v; p = r; }
      }
      s_piv = p;
    }
    __syncthreads();
    const int p = s_piv;
    // --- row swap (16 threads, one per column) ---
    if (p != k && tid < DIM) {
      float t0 = M[k][tid]; M[k][tid] = M[p][tid]; M[p][tid] = t0;
      float t1 = Inv[k][tid]; Inv[k][tid] = Inv[p][tid]; Inv[p][tid] = t1;
    }
    __syncthreads();
    // --- everyone reads the pivot BEFORE row k is normalized ---
    const float pivinv = 1.0f / M[k][k];
    __syncthreads();
    if (i == k) { M[k][j] *= pivinv; Inv[k][j] *= pivinv; }
    __syncthreads();
    // --- read elimination factor before anyone overwrites column k ---
    const float f = M[i][k];
    __syncthreads();
    if (i != k) {
      M[i][j] -= f * M[k][j];
      Inv[i][j] -= f * Inv[k][j];
    }
    __syncthreads();
  }

  // C = B_rep @ A
  float acc = 0.0f;
#pragma unroll
  for (int k = 0; k < DIM; ++k) acc += Bs[i][k] * As[k][j];
  Cs[i][j] = acc;
  __syncthreads();

  // W = inv(A) @ C
  float w = 0.0f;
#pragma unroll
  for (int k = 0; k < DIM; ++k) w += Inv[i][k] * Cs[k][j];
  Wg[n * 256 + i * 16 + j] = w;
}

// ---------------------------------------------------------------------------
// Kernel 2: out[b] = W[a[b]] @ x[b]. One thread per sample.
// W staged in LDS with padded action stride (bank-conflict-free broadcast).
// x loads / out stores fully vectorized as float4.
// ---------------------------------------------------------------------------
__global__ __launch_bounds__(256) void gather_matvec_kernel(
    const float* __restrict__ x, const int* __restrict__ a,
    const float* __restrict__ Wg, float* __restrict__ out, int batch) {
  __shared__ __align__(16) float Wl[N_ACTIONS * W_STRIDE];

  const int tid = threadIdx.x;
  // stage 8 KB of W into padded LDS layout
  for (int idx = tid; idx < N_ACTIONS * 256; idx += 256) {
    Wl[(idx >> 8) * W_STRIDE + (idx & 255)] = Wg[idx];
  }
  __syncthreads();

  const int b = blockIdx.x * 256 + tid;
  if (b >= batch) return;

  const int act = a[b];
  const float4* xp = reinterpret_cast<const float4*>(x + (size_t)b * 16);
  const float4 x0 = xp[0];
  const float4 x1 = xp[1];
  const float4 x2 = xp[2];
  const float4 x3 = xp[3];

  const float* Wp = Wl + act * W_STRIDE;
  float4 o[4];
#pragma unroll
  for (int q = 0; q < 4; ++q) {
    float r[4];
#pragma unroll
    for (int t = 0; t < 4; ++t) {
      const int i = q * 4 + t;
      const float4* wr = reinterpret_cast<const float4*>(Wp + i * 16);
      const float4 w0 = wr[0];
      const float4 w1 = wr[1];
      const float4 w2 = wr[2];
      const float4 w3 = wr[3];
      r[t] = w0.x * x0.x + w0.y * x0.y + w0.z * x0.z + w0.w * x0.w +
             w1.x * x1.x + w1.y * x1.y + w1.z * x1.z + w1.w * x1.w +
             w2.x * x2.x + w2.y * x2.y + w2.z * x2.z + w2.w * x2.w +
             w3.x * x3.x + w3.y * x3.y + w3.z * x3.z + w3.w * x3.w;
    }
    o[q] = make_float4(r[0], r[1], r[2], r[3]);
  }

  float4* op = reinterpret_cast<float4*>(out + (size_t)b * 16);
  op[0] = o[0];
  op[1] = o[1];
  op[2] = o[2];
  op[3] = o[3];
}

extern "C" void kernel_launch(void* const* d_in, const int* in_sizes, int n_in,
                              void* d_out, int out_size, void* d_ws, size_t ws_size,
                              hipStream_t stream) {
  const float* x = (const float*)d_in[0];
  const int* a = (const int*)d_in[1];
  const float* A = (const float*)d_in[2];
  const float* Brep = (const float*)d_in[3];
  float* out = (float*)d_out;
  float* Wg = (float*)d_ws;  // 8*256 floats = 8 KB scratch

  const int batch = in_sizes[1];  // 500000

  compute_W_kernel<<<N_ACTIONS, 256, 0, stream>>>(A, Brep, Wg);
  const int blocks = (batch + 255) / 256;
  gather_matvec_kernel<<<blocks, 256, 0, stream>>>(x, a, Wg, out, batch);
}